// Round 7
// baseline (802.791 us; speedup 1.0000x reference)
//
#include <hip/hip_runtime.h>
#include <math.h>

#define HDIM 1024
#define FDIM 2048   // 2H
#define NEXP 8
#define MTOK 16384  // 8*2048 tokens
#define NSLC 32     // partial-logit slices: 16 bn x 2 wn

// Fragment-major split-bf16 layout for mfma_f32_32x32x16_bf16:
//   af[mt][ks][hl][lane][j]  mt=m>>5 (512), ks=k>>4 (64), hl in {h,l},
//   lane = ((k>>3)&1)*32 + (m&31), j = k&7.   Per (mt): 65536 shorts (128 KB).
//   wf same with nt=n>>5 (64).
// A wave's fragment load = base + lane*16B -> one coalesced 1 KB dwordx4.

typedef __attribute__((ext_vector_type(8))) short bf16x8;    // 4 VGPRs
typedef __attribute__((ext_vector_type(16))) float f32x16;   // 32x32 acc

__device__ inline unsigned short f2bf_rne(float f) {
    unsigned int u = __float_as_uint(f);
    u = (u + 0x7FFFu + ((u >> 16) & 1u)) >> 16;
    return (unsigned short)u;
}
__device__ inline float bf2f(unsigned short h) {
    unsigned int u = ((unsigned int)h) << 16;
    return __uint_as_float(u);
}

// --- Kernel A: x fp32 -> fragment-major split bf16 af (2 k-passes via LDS) ---
__global__ __launch_bounds__(256) void cvt_x(const float* __restrict__ x,
                                             unsigned short* __restrict__ af)
{
    __shared__ unsigned short hs[16384];  // 32 KB  [ks_local 32][lane 64][j 8]
    __shared__ unsigned short ls[16384];  // 32 KB
    const int mt = blockIdx.x;            // 0..511 (32-row tiles)
    const int m = threadIdx.x & 31;
    const int kc = threadIdx.x >> 5;      // 0..7
    const float* src = x + ((size_t)mt * 32 + m) * HDIM;
    unsigned short* dst = af + (size_t)mt * 65536;

    #pragma unroll
    for (int p = 0; p < 2; p++) {
        #pragma unroll
        for (int i = 0; i < 8; i++) {
            int k_local = kc * 64 + i * 8;          // 0..511
            int k = p * 512 + k_local;
            float v[8];
            *(float4*)(v)     = *(const float4*)(src + k);
            *(float4*)(v + 4) = *(const float4*)(src + k + 4);
            union { unsigned short u[8]; uint4 q; } oh, ol;
            #pragma unroll
            for (int j = 0; j < 8; j++) {
                unsigned short h = f2bf_rne(v[j]);
                oh.u[j] = h;
                ol.u[j] = f2bf_rne(v[j] - bf2f(h));
            }
            int ks_l = k_local >> 4;                // 0..31
            int lane = ((k_local >> 3) & 1) * 32 + m;
            int o = ks_l * 512 + lane * 8;
            *(uint4*)(hs + o) = oh.q;
            *(uint4*)(ls + o) = ol.q;
        }
        __syncthreads();
        // write 32768 shorts (64 KB) contiguous: f = ks_l*1024 + hl*512 + rest
        unsigned short* dp = dst + p * 32768;
        #pragma unroll
        for (int c = 0; c < 16; c++) {
            int f = c * 2048 + threadIdx.x * 8;
            int ks_l = f >> 10, hl = (f >> 9) & 1, rest = f & 511;
            const unsigned short* s = (hl ? ls : hs) + ks_l * 512 + rest;
            *(uint4*)(dp + f) = *(const uint4*)s;
        }
        __syncthreads();
    }
}

// --- Kernel B: w1 [K][N] fp32 -> fragment-major split bf16 wf ---
__global__ __launch_bounds__(256) void cvt_w1f(const float* __restrict__ w1,
                                               unsigned short* __restrict__ wf)
{
    __shared__ float t[32][33];
    int n0 = blockIdx.x * 32;   // over FDIM
    int k0 = blockIdx.y * 32;   // over HDIM
    int lx = threadIdx.x & 31, ly = threadIdx.x >> 5;  // 32 x 8
    #pragma unroll
    for (int r = 0; r < 32; r += 8)
        t[ly + r][lx] = w1[(size_t)(k0 + ly + r) * FDIM + n0 + lx];
    __syncthreads();
    #pragma unroll
    for (int r = 0; r < 32; r += 8) {
        float v = t[lx][ly + r];
        unsigned short h = f2bf_rne(v);
        unsigned short l = f2bf_rne(v - bf2f(h));
        int n = n0 + ly + r, k = k0 + lx;
        size_t base = ((size_t)(n >> 5) * 64 + (k >> 4)) * 1024;
        int lj = (((k >> 3) & 1) * 32 + (n & 31)) * 8 + (k & 7);
        wf[base + lj] = h;
        wf[base + 512 + lj] = l;
    }
}

// --- Kernel C: split-bf16 GEMM1, 32x32x16 MFMA, no LDS, no barriers. ---
// Block 256x128 (4 waves 2x2); wave 128x64 via 4x2 frags of 32x32, k-step 16.
// acc += ah*bh + ah*bl + al*bh per step (al*bl dropped: 2^-18 rel).
__global__ __launch_bounds__(256, 2) void gemm1_mfma(
    const unsigned short* __restrict__ af, const unsigned short* __restrict__ wf,
    const float* __restrict__ b1, const float* __restrict__ w2,
    float* __restrict__ part)
{
    const int tid  = threadIdx.x;
    const int lane = tid & 63;
    const int l31  = lane & 31;
    const int half = lane >> 5;
    const int wave = tid >> 6;
    const int wm   = wave & 1;
    const int wn   = wave >> 1;

    // XCD swizzle: per XCD, walk (strip of 2 bm) x 16 bn, bmo inner.
    // A hot/XCD = 2 bm x 256 rows x 4 KB = 2 MB; B tile 512 KB -> fits L2.
    const int id = blockIdx.x;          // 0..1023
    const int xcd = id & 7, seq = id >> 3;      // seq 0..127
    const int strip = seq >> 5;                 // 0..3
    const int bn = (seq >> 1) & 15;
    const int bmo = seq & 1;
    const int bm = strip * 16 + xcd * 2 + bmo;  // 0..63
    const int m0 = bm * 256, n0 = bn * 128;

    const unsigned short* ap[4];
    const unsigned short* bp[2];
    #pragma unroll
    for (int i = 0; i < 4; i++)
        ap[i] = af + (size_t)(bm * 8 + wm * 4 + i) * 65536 + lane * 8;
    #pragma unroll
    for (int j = 0; j < 2; j++)
        bp[j] = wf + (size_t)(bn * 4 + wn * 2 + j) * 65536 + lane * 8;

    f32x16 acc[4][2];
    #pragma unroll
    for (int i = 0; i < 4; i++)
        #pragma unroll
        for (int j = 0; j < 2; j++)
            #pragma unroll
            for (int r = 0; r < 16; r++) acc[i][j][r] = 0.f;

    bf16x8 Ah0[4], Al0[4], Bh0[2], Bl0[2];
    bf16x8 Ah1[4], Al1[4], Bh1[2], Bl1[2];

    // ks = 0 into buf0
    #pragma unroll
    for (int i = 0; i < 4; i++) {
        Ah0[i] = *(const bf16x8*)(ap[i]);
        Al0[i] = *(const bf16x8*)(ap[i] + 512);
    }
    #pragma unroll
    for (int j = 0; j < 2; j++) {
        Bh0[j] = *(const bf16x8*)(bp[j]);
        Bl0[j] = *(const bf16x8*)(bp[j] + 512);
    }

    #pragma unroll 1
    for (int t = 0; t < 64; t += 2) {
        // prefetch ks = t+1 into buf1 (offsets 1024/1536 shorts = 2/3 KB imm)
        #pragma unroll
        for (int i = 0; i < 4; i++) {
            Ah1[i] = *(const bf16x8*)(ap[i] + 1024);
            Al1[i] = *(const bf16x8*)(ap[i] + 1536);
        }
        #pragma unroll
        for (int j = 0; j < 2; j++) {
            Bh1[j] = *(const bf16x8*)(bp[j] + 1024);
            Bl1[j] = *(const bf16x8*)(bp[j] + 1536);
        }
        // compute ks = t
        #pragma unroll
        for (int i = 0; i < 4; i++)
            #pragma unroll
            for (int j = 0; j < 2; j++) {
                acc[i][j] = __builtin_amdgcn_mfma_f32_32x32x16_bf16(
                    Ah0[i], Bh0[j], acc[i][j], 0, 0, 0);
                acc[i][j] = __builtin_amdgcn_mfma_f32_32x32x16_bf16(
                    Ah0[i], Bl0[j], acc[i][j], 0, 0, 0);
                acc[i][j] = __builtin_amdgcn_mfma_f32_32x32x16_bf16(
                    Al0[i], Bh0[j], acc[i][j], 0, 0, 0);
            }
        // advance window; prefetch ks = t+2 into buf0
        #pragma unroll
        for (int i = 0; i < 4; i++) ap[i] += 2048;
        #pragma unroll
        for (int j = 0; j < 2; j++) bp[j] += 2048;
        if (t + 2 < 64) {
            #pragma unroll
            for (int i = 0; i < 4; i++) {
                Ah0[i] = *(const bf16x8*)(ap[i]);
                Al0[i] = *(const bf16x8*)(ap[i] + 512);
            }
            #pragma unroll
            for (int j = 0; j < 2; j++) {
                Bh0[j] = *(const bf16x8*)(bp[j]);
                Bl0[j] = *(const bf16x8*)(bp[j] + 512);
            }
        }
        // compute ks = t+1
        #pragma unroll
        for (int i = 0; i < 4; i++)
            #pragma unroll
            for (int j = 0; j < 2; j++) {
                acc[i][j] = __builtin_amdgcn_mfma_f32_32x32x16_bf16(
                    Ah1[i], Bh1[j], acc[i][j], 0, 0, 0);
                acc[i][j] = __builtin_amdgcn_mfma_f32_32x32x16_bf16(
                    Ah1[i], Bl1[j], acc[i][j], 0, 0, 0);
                acc[i][j] = __builtin_amdgcn_mfma_f32_32x32x16_bf16(
                    Al1[i], Bh1[j], acc[i][j], 0, 0, 0);
            }
    }

    // --- epilogue: bias + exact GELU ---
    // C/D 32x32: col(n) = lane&31, row(m) = (r&3) + 8*(r>>2) + 4*(lane>>5)
    #pragma unroll
    for (int j = 0; j < 2; j++) {
        int n = n0 + wn * 64 + j * 32 + l31;
        float bb = b1[n];
        #pragma unroll
        for (int i = 0; i < 4; i++)
            #pragma unroll
            for (int r = 0; r < 16; r++) {
                float v = acc[i][j][r] + bb;
                acc[i][j][r] = 0.5f * v * (1.0f + erff(v * 0.70710678118654752f));
            }
    }

    // w2 rows for this lane's 2 n-columns
    float w2r[2][8];
    #pragma unroll
    for (int j = 0; j < 2; j++) {
        const float4* p = (const float4*)(w2 + (size_t)(n0 + wn * 64 + j * 32 + l31) * NEXP);
        float4 u = p[0], v = p[1];
        w2r[j][0] = u.x; w2r[j][1] = u.y; w2r[j][2] = u.z; w2r[j][3] = u.w;
        w2r[j][4] = v.x; w2r[j][5] = v.y; w2r[j][6] = v.z; w2r[j][7] = v.w;
    }

    const int sl = bn * 2 + wn;  // partial slice (deterministic)
    #pragma unroll
    for (int e = 0; e < NEXP; e++) {
        float p[4][16];
        #pragma unroll
        for (int i = 0; i < 4; i++)
            #pragma unroll
            for (int r = 0; r < 16; r++)
                p[i][r] = acc[i][0][r] * w2r[0][e] + acc[i][1][r] * w2r[1][e];
        #pragma unroll
        for (int off = 1; off < 32; off <<= 1)
            #pragma unroll
            for (int i = 0; i < 4; i++)
                #pragma unroll
                for (int r = 0; r < 16; r++)
                    p[i][r] += __shfl_xor(p[i][r], off);
        if (l31 == 0) {
            #pragma unroll
            for (int i = 0; i < 4; i++)
                #pragma unroll
                for (int r = 0; r < 16; r++) {
                    int m = m0 + wm * 128 + i * 32 + (r & 3) + 8 * (r >> 2) + 4 * half;
                    part[(size_t)sl * (MTOK * NEXP) + (size_t)m * NEXP + e] = p[i][r];
                }
        }
    }
}

// --- Kernel 2: deterministic sum of 32 slices -> logits, top-2, softmax ---
__global__ __launch_bounds__(256) void router_topk(
    const float* __restrict__ part, const float* __restrict__ b2,
    float* __restrict__ out, float* __restrict__ gu, int* __restrict__ gc)
{
    const int t = blockIdx.x * 256 + threadIdx.x;

    float logit[8];
    #pragma unroll
    for (int e = 0; e < 8; e++) logit[e] = b2[e];
    #pragma unroll
    for (int j = 0; j < NSLC; j++) {
        const float4* p4 = (const float4*)(part + (size_t)j * (MTOK * NEXP) + (size_t)t * NEXP);
        float4 u = p4[0], v = p4[1];
        logit[0] += u.x; logit[1] += u.y; logit[2] += u.z; logit[3] += u.w;
        logit[4] += v.x; logit[5] += v.y; logit[6] += v.z; logit[7] += v.w;
    }

    int i1 = 0; float v1 = logit[0];
    #pragma unroll
    for (int e = 1; e < 8; e++) { if (logit[e] > v1) { v1 = logit[e]; i1 = e; } }
    int i2 = -1; float v2 = -INFINITY;
    #pragma unroll
    for (int e = 0; e < 8; e++) {
        if (e != i1 && logit[e] > v2) { v2 = logit[e]; i2 = e; }
    }
    float ex = expf(v2 - v1);
    float inv = 1.0f / (1.0f + ex);
    float wa = inv, wb = ex * inv;

    float4* o = (float4*)(out + (size_t)t * NEXP);
    o[0] = make_float4(logit[0], logit[1], logit[2], logit[3]);
    o[1] = make_float4(logit[4], logit[5], logit[6], logit[7]);

    float mk[8];
    #pragma unroll
    for (int e = 0; e < 8; e++) mk[e] = 0.0f;
    mk[i1] = wa; mk[i2] = wb;
    float4* om = (float4*)(out + (size_t)(MTOK * NEXP) + (size_t)t * NEXP);
    om[0] = make_float4(mk[0], mk[1], mk[2], mk[3]);
    om[1] = make_float4(mk[4], mk[5], mk[6], mk[7]);

    __shared__ float us[8];
    __shared__ int cs;
    if (threadIdx.x < 8) us[threadIdx.x] = 0.0f;
    if (threadIdx.x == 0) cs = 0;
    __syncthreads();
    atomicAdd(&us[i1], wa);
    atomicAdd(&us[i2], wb);
    int cnt = (wa > 0.0f ? 1 : 0) + (wb > 0.0f ? 1 : 0);
    atomicAdd(&cs, cnt);
    __syncthreads();
    if (threadIdx.x < 8) atomicAdd(&gu[threadIdx.x], us[threadIdx.x]);
    if (threadIdx.x == 0) atomicAdd(gc, cs);
}

// --- Kernel 3: finalize losses + normalized usage ---
__global__ void router_final(const float* __restrict__ gu, const int* __restrict__ gc,
                             float* __restrict__ out)
{
    if (blockIdx.x == 0 && threadIdx.x == 0) {
        float u[8]; float tot = 0.0f;
        for (int e = 0; e < 8; e++) { u[e] = gu[e]; tot += u[e]; }
        float lb = 0.0f;
        for (int e = 0; e < 8; e++) {
            float un = u[e] / tot;
            out[2 * MTOK * NEXP + 1 + e] = un;
            float d = un - 0.125f;
            lb += d * d;
        }
        lb *= (1.0f / 8.0f);
        float sp = ((float)(*gc) / (float)MTOK) * 0.5f;
        out[2 * MTOK * NEXP] = lb + 0.1f * sp;
    }
}

extern "C" void kernel_launch(void* const* d_in, const int* in_sizes, int n_in,
                              void* d_out, int out_size, void* d_ws, size_t ws_size,
                              hipStream_t stream) {
    const float* x  = (const float*)d_in[0];
    const float* w1 = (const float*)d_in[1];
    const float* b1 = (const float*)d_in[2];
    const float* w2 = (const float*)d_in[3];
    const float* b2 = (const float*)d_in[4];
    float* out = (float*)d_out;

    unsigned short* af = (unsigned short*)d_ws;            // 512*65536*2 B = 64 MiB
    unsigned short* wf = af + (size_t)512 * 65536;         // 64*65536*2 B = 8 MiB
    float* part = (float*)(wf + (size_t)64 * 65536);       // 16 MiB
    float* gu = part + (size_t)NSLC * MTOK * NEXP;
    int* gc = (int*)(gu + 8);

    hipMemsetAsync(gu, 0, 64, stream);

    cvt_x<<<512, 256, 0, stream>>>(x, af);
    cvt_w1f<<<dim3(FDIM / 32, HDIM / 32), 256, 0, stream>>>(w1, wf);
    gemm1_mfma<<<1024, 256, 0, stream>>>(af, wf, b1, w2, part);
    router_topk<<<MTOK / 256, 256, 0, stream>>>(part, b2, out, gu, gc);
    router_final<<<1, 64, 0, stream>>>(gu, gc, out);
}

// Round 8
// 409.947 us; speedup vs baseline: 1.9583x; 1.9583x over previous
//
#include <hip/hip_runtime.h>
#include <math.h>

#define HDIM 1024
#define FDIM 2048   // 2H
#define NEXP 8
#define MTOK 16384  // 8*2048 tokens
#define NSLC 32     // partial-logit slices: 16 bn x 2 wn

// Fragment-major split-bf16 layout for mfma_f32_32x32x16_bf16:
//   af[mt][ks][hl][lane][j]  mt=m>>5 (512), ks=k>>4 (64), hl in {h,l},
//   lane = ((k>>3)&1)*32 + (m&31), j = k&7.   Per (mt): 65536 shorts (128 KB).
//   wf same with nt=n>>5 (64).
// A wave's fragment load = base + lane*16B -> one coalesced 1 KB dwordx4.
// (A/B and C/D layouts verified end-to-end in round 7: absmax passed.)

typedef __attribute__((ext_vector_type(8))) short bf16x8;    // 4 VGPRs
typedef __attribute__((ext_vector_type(16))) float f32x16;   // 32x32 acc

__device__ inline unsigned short f2bf_rne(float f) {
    unsigned int u = __float_as_uint(f);
    u = (u + 0x7FFFu + ((u >> 16) & 1u)) >> 16;
    return (unsigned short)u;
}
__device__ inline float bf2f(unsigned short h) {
    unsigned int u = ((unsigned int)h) << 16;
    return __uint_as_float(u);
}

// --- Kernel A: x fp32 -> fragment-major split bf16 af (2 k-passes via LDS) ---
__global__ __launch_bounds__(256) void cvt_x(const float* __restrict__ x,
                                             unsigned short* __restrict__ af)
{
    __shared__ unsigned short hs[16384];  // 32 KB  [ks_local 32][lane 64][j 8]
    __shared__ unsigned short ls[16384];  // 32 KB
    const int mt = blockIdx.x;            // 0..511 (32-row tiles)
    const int m = threadIdx.x & 31;
    const int kc = threadIdx.x >> 5;      // 0..7
    const float* src = x + ((size_t)mt * 32 + m) * HDIM;
    unsigned short* dst = af + (size_t)mt * 65536;

    #pragma unroll
    for (int p = 0; p < 2; p++) {
        #pragma unroll
        for (int i = 0; i < 8; i++) {
            int k_local = kc * 64 + i * 8;          // 0..511
            int k = p * 512 + k_local;
            float v[8];
            *(float4*)(v)     = *(const float4*)(src + k);
            *(float4*)(v + 4) = *(const float4*)(src + k + 4);
            union { unsigned short u[8]; uint4 q; } oh, ol;
            #pragma unroll
            for (int j = 0; j < 8; j++) {
                unsigned short h = f2bf_rne(v[j]);
                oh.u[j] = h;
                ol.u[j] = f2bf_rne(v[j] - bf2f(h));
            }
            int ks_l = k_local >> 4;                // 0..31
            int lane = ((k_local >> 3) & 1) * 32 + m;
            int o = ks_l * 512 + lane * 8;
            *(uint4*)(hs + o) = oh.q;
            *(uint4*)(ls + o) = ol.q;
        }
        __syncthreads();
        unsigned short* dp = dst + p * 32768;
        #pragma unroll
        for (int c = 0; c < 16; c++) {
            int f = c * 2048 + threadIdx.x * 8;
            int ks_l = f >> 10, hl = (f >> 9) & 1, rest = f & 511;
            const unsigned short* s = (hl ? ls : hs) + ks_l * 512 + rest;
            *(uint4*)(dp + f) = *(const uint4*)s;
        }
        __syncthreads();
    }
}

// --- Kernel B: w1 [K][N] fp32 -> fragment-major split bf16 wf ---
__global__ __launch_bounds__(256) void cvt_w1f(const float* __restrict__ w1,
                                               unsigned short* __restrict__ wf)
{
    __shared__ float t[32][33];
    int n0 = blockIdx.x * 32;   // over FDIM
    int k0 = blockIdx.y * 32;   // over HDIM
    int lx = threadIdx.x & 31, ly = threadIdx.x >> 5;  // 32 x 8
    #pragma unroll
    for (int r = 0; r < 32; r += 8)
        t[ly + r][lx] = w1[(size_t)(k0 + ly + r) * FDIM + n0 + lx];
    __syncthreads();
    #pragma unroll
    for (int r = 0; r < 32; r += 8) {
        float v = t[lx][ly + r];
        unsigned short h = f2bf_rne(v);
        unsigned short l = f2bf_rne(v - bf2f(h));
        int n = n0 + ly + r, k = k0 + lx;
        size_t base = ((size_t)(n >> 5) * 64 + (k >> 4)) * 1024;
        int lj = (((k >> 3) & 1) * 32 + (n & 31)) * 8 + (k & 7);
        wf[base + lj] = h;
        wf[base + 512 + lj] = l;
    }
}

// --- Kernel C: split-bf16 GEMM1, 32x32x16 MFMA, no LDS, no barriers. ---
// Block 128x128 (4 waves 2x2); wave 64x64 via 2x2 frags of 32x32, k-step 16.
// acc += ah*bh + ah*bl + al*bh in 3 passes of 4 independent MFMAs each
// (reuse distance 4 hides accumulate latency). 3 waves/SIMD for TLP.
__global__ __launch_bounds__(256, 3) void gemm1_mfma(
    const unsigned short* __restrict__ af, const unsigned short* __restrict__ wf,
    const float* __restrict__ b1, const float* __restrict__ w2,
    float* __restrict__ part)
{
    const int tid  = threadIdx.x;
    const int lane = tid & 63;
    const int l31  = lane & 31;
    const int half = lane >> 5;
    const int wave = tid >> 6;
    const int wm   = wave & 1;
    const int wn   = wave >> 1;

    // XCD swizzle: per XCD walk (4 strips) x 16 bn x 4 bmo; A hot/XCD = 2 MB,
    // B tile 512 KB -> fits the 4 MB per-XCD L2.
    const int id = blockIdx.x;                  // 0..2047
    const int xcd = id & 7, seq = id >> 3;      // seq 0..255
    const int strip = seq >> 6;                 // 0..3
    const int bn = (seq >> 2) & 15;
    const int bmo = seq & 3;
    const int bm = strip * 32 + xcd * 4 + bmo;  // 0..127
    const int m0 = bm * 128, n0 = bn * 128;

    const unsigned short* ap[2];
    const unsigned short* bp[2];
    #pragma unroll
    for (int i = 0; i < 2; i++)
        ap[i] = af + (size_t)(bm * 4 + wm * 2 + i) * 65536 + lane * 8;
    #pragma unroll
    for (int j = 0; j < 2; j++)
        bp[j] = wf + (size_t)(bn * 4 + wn * 2 + j) * 65536 + lane * 8;

    f32x16 acc[2][2];
    #pragma unroll
    for (int i = 0; i < 2; i++)
        #pragma unroll
        for (int j = 0; j < 2; j++)
            #pragma unroll
            for (int r = 0; r < 16; r++) acc[i][j][r] = 0.f;

    bf16x8 Ah0[2], Al0[2], Bh0[2], Bl0[2];
    bf16x8 Ah1[2], Al1[2], Bh1[2], Bl1[2];

    // ks = 0 into buf0
    #pragma unroll
    for (int i = 0; i < 2; i++) {
        Ah0[i] = *(const bf16x8*)(ap[i]);
        Al0[i] = *(const bf16x8*)(ap[i] + 512);
        Bh0[i] = *(const bf16x8*)(bp[i]);
        Bl0[i] = *(const bf16x8*)(bp[i] + 512);
    }

    #pragma unroll 1
    for (int t = 0; t < 64; t += 2) {
        // prefetch ks = t+1 into buf1 (imm offsets 2048/3072 B)
        #pragma unroll
        for (int i = 0; i < 2; i++) {
            Ah1[i] = *(const bf16x8*)(ap[i] + 1024);
            Al1[i] = *(const bf16x8*)(ap[i] + 1536);
            Bh1[i] = *(const bf16x8*)(bp[i] + 1024);
            Bl1[i] = *(const bf16x8*)(bp[i] + 1536);
        }
        // compute ks = t : 3 passes x 4 independent MFMAs
        #pragma unroll
        for (int i = 0; i < 2; i++)
            #pragma unroll
            for (int j = 0; j < 2; j++)
                acc[i][j] = __builtin_amdgcn_mfma_f32_32x32x16_bf16(
                    Ah0[i], Bh0[j], acc[i][j], 0, 0, 0);
        #pragma unroll
        for (int i = 0; i < 2; i++)
            #pragma unroll
            for (int j = 0; j < 2; j++)
                acc[i][j] = __builtin_amdgcn_mfma_f32_32x32x16_bf16(
                    Ah0[i], Bl0[j], acc[i][j], 0, 0, 0);
        #pragma unroll
        for (int i = 0; i < 2; i++)
            #pragma unroll
            for (int j = 0; j < 2; j++)
                acc[i][j] = __builtin_amdgcn_mfma_f32_32x32x16_bf16(
                    Al0[i], Bh0[j], acc[i][j], 0, 0, 0);
        // advance window; prefetch ks = t+2 into buf0 (last iter: discarded)
        #pragma unroll
        for (int i = 0; i < 2; i++) { ap[i] += 2048; bp[i] += 2048; }
        #pragma unroll
        for (int i = 0; i < 2; i++) {
            Ah0[i] = *(const bf16x8*)(ap[i]);
            Al0[i] = *(const bf16x8*)(ap[i] + 512);
            Bh0[i] = *(const bf16x8*)(bp[i]);
            Bl0[i] = *(const bf16x8*)(bp[i] + 512);
        }
        // compute ks = t+1
        #pragma unroll
        for (int i = 0; i < 2; i++)
            #pragma unroll
            for (int j = 0; j < 2; j++)
                acc[i][j] = __builtin_amdgcn_mfma_f32_32x32x16_bf16(
                    Ah1[i], Bh1[j], acc[i][j], 0, 0, 0);
        #pragma unroll
        for (int i = 0; i < 2; i++)
            #pragma unroll
            for (int j = 0; j < 2; j++)
                acc[i][j] = __builtin_amdgcn_mfma_f32_32x32x16_bf16(
                    Ah1[i], Bl1[j], acc[i][j], 0, 0, 0);
        #pragma unroll
        for (int i = 0; i < 2; i++)
            #pragma unroll
            for (int j = 0; j < 2; j++)
                acc[i][j] = __builtin_amdgcn_mfma_f32_32x32x16_bf16(
                    Al1[i], Bh1[j], acc[i][j], 0, 0, 0);

        // enforce VMEM:MFMA interleave (16 loads : 24 MFMA per body)
        #pragma unroll
        for (int g = 0; g < 8; g++) {
            __builtin_amdgcn_sched_group_barrier(0x020, 2, 0);  // 2 VMEM read
            __builtin_amdgcn_sched_group_barrier(0x008, 3, 0);  // 3 MFMA
        }
    }

    // --- epilogue: bias + exact GELU ---
    // C/D 32x32: col(n) = lane&31, row(m) = (r&3) + 8*(r>>2) + 4*(lane>>5)
    #pragma unroll
    for (int j = 0; j < 2; j++) {
        int n = n0 + wn * 64 + j * 32 + l31;
        float bb = b1[n];
        #pragma unroll
        for (int i = 0; i < 2; i++)
            #pragma unroll
            for (int r = 0; r < 16; r++) {
                float v = acc[i][j][r] + bb;
                acc[i][j][r] = 0.5f * v * (1.0f + erff(v * 0.70710678118654752f));
            }
    }

    // w2 rows for this lane's 2 n-columns
    float w2r[2][8];
    #pragma unroll
    for (int j = 0; j < 2; j++) {
        const float4* p = (const float4*)(w2 + (size_t)(n0 + wn * 64 + j * 32 + l31) * NEXP);
        float4 u = p[0], v = p[1];
        w2r[j][0] = u.x; w2r[j][1] = u.y; w2r[j][2] = u.z; w2r[j][3] = u.w;
        w2r[j][4] = v.x; w2r[j][5] = v.y; w2r[j][6] = v.z; w2r[j][7] = v.w;
    }

    const int sl = bn * 2 + wn;  // partial slice (deterministic)
    #pragma unroll
    for (int e = 0; e < NEXP; e++) {
        float p[2][16];
        #pragma unroll
        for (int i = 0; i < 2; i++)
            #pragma unroll
            for (int r = 0; r < 16; r++)
                p[i][r] = acc[i][0][r] * w2r[0][e] + acc[i][1][r] * w2r[1][e];
        #pragma unroll
        for (int off = 1; off < 32; off <<= 1)
            #pragma unroll
            for (int i = 0; i < 2; i++)
                #pragma unroll
                for (int r = 0; r < 16; r++)
                    p[i][r] += __shfl_xor(p[i][r], off);
        if (l31 == 0) {
            #pragma unroll
            for (int i = 0; i < 2; i++)
                #pragma unroll
                for (int r = 0; r < 16; r++) {
                    int m = m0 + wm * 64 + i * 32 + (r & 3) + 8 * (r >> 2) + 4 * half;
                    part[(size_t)sl * (MTOK * NEXP) + (size_t)m * NEXP + e] = p[i][r];
                }
        }
    }
}

// --- Kernel 2: deterministic sum of 32 slices -> logits, top-2, softmax ---
__global__ __launch_bounds__(256) void router_topk(
    const float* __restrict__ part, const float* __restrict__ b2,
    float* __restrict__ out, float* __restrict__ gu, int* __restrict__ gc)
{
    const int t = blockIdx.x * 256 + threadIdx.x;

    float logit[8];
    #pragma unroll
    for (int e = 0; e < 8; e++) logit[e] = b2[e];
    #pragma unroll
    for (int j = 0; j < NSLC; j++) {
        const float4* p4 = (const float4*)(part + (size_t)j * (MTOK * NEXP) + (size_t)t * NEXP);
        float4 u = p4[0], v = p4[1];
        logit[0] += u.x; logit[1] += u.y; logit[2] += u.z; logit[3] += u.w;
        logit[4] += v.x; logit[5] += v.y; logit[6] += v.z; logit[7] += v.w;
    }

    int i1 = 0; float v1 = logit[0];
    #pragma unroll
    for (int e = 1; e < 8; e++) { if (logit[e] > v1) { v1 = logit[e]; i1 = e; } }
    int i2 = -1; float v2 = -INFINITY;
    #pragma unroll
    for (int e = 0; e < 8; e++) {
        if (e != i1 && logit[e] > v2) { v2 = logit[e]; i2 = e; }
    }
    float ex = expf(v2 - v1);
    float inv = 1.0f / (1.0f + ex);
    float wa = inv, wb = ex * inv;

    float4* o = (float4*)(out + (size_t)t * NEXP);
    o[0] = make_float4(logit[0], logit[1], logit[2], logit[3]);
    o[1] = make_float4(logit[4], logit[5], logit[6], logit[7]);

    float mk[8];
    #pragma unroll
    for (int e = 0; e < 8; e++) mk[e] = 0.0f;
    mk[i1] = wa; mk[i2] = wb;
    float4* om = (float4*)(out + (size_t)(MTOK * NEXP) + (size_t)t * NEXP);
    om[0] = make_float4(mk[0], mk[1], mk[2], mk[3]);
    om[1] = make_float4(mk[4], mk[5], mk[6], mk[7]);

    __shared__ float us[8];
    __shared__ int cs;
    if (threadIdx.x < 8) us[threadIdx.x] = 0.0f;
    if (threadIdx.x == 0) cs = 0;
    __syncthreads();
    atomicAdd(&us[i1], wa);
    atomicAdd(&us[i2], wb);
    int cnt = (wa > 0.0f ? 1 : 0) + (wb > 0.0f ? 1 : 0);
    atomicAdd(&cs, cnt);
    __syncthreads();
    if (threadIdx.x < 8) atomicAdd(&gu[threadIdx.x], us[threadIdx.x]);
    if (threadIdx.x == 0) atomicAdd(gc, cs);
}

// --- Kernel 3: finalize losses + normalized usage ---
__global__ void router_final(const float* __restrict__ gu, const int* __restrict__ gc,
                             float* __restrict__ out)
{
    if (blockIdx.x == 0 && threadIdx.x == 0) {
        float u[8]; float tot = 0.0f;
        for (int e = 0; e < 8; e++) { u[e] = gu[e]; tot += u[e]; }
        float lb = 0.0f;
        for (int e = 0; e < 8; e++) {
            float un = u[e] / tot;
            out[2 * MTOK * NEXP + 1 + e] = un;
            float d = un - 0.125f;
            lb += d * d;
        }
        lb *= (1.0f / 8.0f);
        float sp = ((float)(*gc) / (float)MTOK) * 0.5f;
        out[2 * MTOK * NEXP] = lb + 0.1f * sp;
    }
}

extern "C" void kernel_launch(void* const* d_in, const int* in_sizes, int n_in,
                              void* d_out, int out_size, void* d_ws, size_t ws_size,
                              hipStream_t stream) {
    const float* x  = (const float*)d_in[0];
    const float* w1 = (const float*)d_in[1];
    const float* b1 = (const float*)d_in[2];
    const float* w2 = (const float*)d_in[3];
    const float* b2 = (const float*)d_in[4];
    float* out = (float*)d_out;

    unsigned short* af = (unsigned short*)d_ws;            // 512*65536*2 B = 64 MiB
    unsigned short* wf = af + (size_t)512 * 65536;         // 64*65536*2 B = 8 MiB
    float* part = (float*)(wf + (size_t)64 * 65536);       // 16 MiB
    float* gu = part + (size_t)NSLC * MTOK * NEXP;
    int* gc = (int*)(gu + 8);

    hipMemsetAsync(gu, 0, 64, stream);

    cvt_x<<<512, 256, 0, stream>>>(x, af);
    cvt_w1f<<<dim3(FDIM / 32, HDIM / 32), 256, 0, stream>>>(w1, wf);
    gemm1_mfma<<<2048, 256, 0, stream>>>(af, wf, b1, w2, part);
    router_topk<<<MTOK / 256, 256, 0, stream>>>(part, b2, out, gu, gc);
    router_final<<<1, 64, 0, stream>>>(gu, gc, out);
}